// Round 3
// baseline (339.250 us; speedup 1.0000x reference)
//
#include <hip/hip_runtime.h>
#include <stdint.h>

// BertSelfAttention fused forward, MI355X/gfx950.
// Pipeline: [conv_x_k] fp32->bf16 X | [wtrans_k] W -> W^T bf16 | [qkv_gemm]
// bf16 MFMA GEMM -> Q,K [B,NH,S,HD] + V^T [B,NH,HD,S] | [attn_fwd] flash attn
// with swapped-operand QK^T (P^T lands in PV fragment layout natively).
// All bf16 handled as raw ushort; conversions are manual RNE.

typedef float  f32x4  __attribute__((ext_vector_type(4)));
typedef short  short8 __attribute__((ext_vector_type(8)));
typedef unsigned short u16;
typedef u16    u16x4  __attribute__((ext_vector_type(4)));
typedef u16    u16x8  __attribute__((ext_vector_type(8)));

#define MFMA_BF16_16x16x32 __builtin_amdgcn_mfma_f32_16x16x32_bf16

// global->LDS direct copy, 16B per lane; LDS dest must be wave-uniform base.
#define GLD16(gp, sp)                                                          \
  __builtin_amdgcn_global_load_lds(                                            \
      (const __attribute__((address_space(1))) void*)(gp),                     \
      (__attribute__((address_space(3))) void*)(sp), 16, 0, 0)

__device__ __forceinline__ u16 f2bf(float f) {  // RNE fp32->bf16
  unsigned u = __float_as_uint(f);
  return (u16)((u + 0x7FFFu + ((u >> 16) & 1u)) >> 16);
}

// ---------------------------------------------------------------------------
// Kernel 0a: X [8192,1024] fp32 -> bf16.  8192 blocks * 256 thr * 4 elems.
__global__ __launch_bounds__(256) void conv_x_k(const float* __restrict__ x,
                                                u16* __restrict__ xb) {
  const int i = (blockIdx.x * 256 + threadIdx.x) * 4;
  const f32x4 v = *(const f32x4*)(x + i);
  u16x4 o;
#pragma unroll
  for (int j = 0; j < 4; ++j) o[j] = f2bf(v[j]);
  *(u16x4*)(xb + i) = o;
}

// ---------------------------------------------------------------------------
// Kernel 0b: Wt[z][n][k] = bf16(W_z[k][n]).  Coalesced reads (lanes span n),
// 16B scattered stores (L2 assembles lines).  512 blocks per z, 3 z.
__global__ __launch_bounds__(256) void wtrans_k(const float* __restrict__ Wq,
                                                const float* __restrict__ Wk,
                                                const float* __restrict__ Wv,
                                                u16* __restrict__ Wt) {
  const int bx = blockIdx.x;
  const int z = bx >> 9;
  const float* W = (z == 0) ? Wq : ((z == 1) ? Wk : Wv);
  const int r = ((bx & 511) << 8) | threadIdx.x;  // 0..131071
  const int kc = r >> 10;                         // 0..127 (8 k's each)
  const int n = r & 1023;
  u16x8 o;
#pragma unroll
  for (int j = 0; j < 8; ++j) o[j] = f2bf(W[(kc * 8 + j) * 1024 + n]);
  *(u16x8*)(Wt + (size_t)z * 1048576 + n * 1024 + kc * 8) = o;
}

// ---------------------------------------------------------------------------
// Kernel 1: C_z = X * W_z + b_z, 128x128 tile, BK=32, 4 waves of 64x64.
// A tile = Xb rows [bm..bm+128) x 32 k (64B rows), B tile = Wt rows (=n cols).
// Both staged via global_load_lds with pre-swizzled source; swizzle
// SWV(row) = ((row>>1)&3)<<4 on the 64B rows -> conflict-free ds_read_b128.
// z<2 -> [B,NH,S,HD] bf16; z==2 -> V^T [B,NH,HD,S] bf16.
__global__ __launch_bounds__(256) void qkv_gemm(
    const u16* __restrict__ Xb, const u16* __restrict__ Wt,
    const float* __restrict__ bq, const float* __restrict__ bk,
    const float* __restrict__ bv, u16* __restrict__ qkv) {
  __shared__ u16 Alds[4096];  // [128][32] swizzled
  __shared__ u16 Blds[4096];  // [128][32] swizzled (rows = n)
  const int tid = threadIdx.x;
  const int l = tid & 63, w = tid >> 6;
  const int c = l & 15, g = l >> 4;
  const int nz = blockIdx.x;          // 0..23 ; consecutive blocks share X panel
  const int z = nz >> 3;
  const int bn = (nz & 7) << 7;
  const int bm = blockIdx.y << 7;
  const u16* wz = Wt + (size_t)z * 1048576;
  const float* bias = (z == 0) ? bq : ((z == 1) ? bk : bv);

  // staging: wave w covers rows 32w..32w+31, two 16-row chunks.
  // lane: row = chunk + (l>>2); src col elems = ((l&3)^((l>>3)&3))*8
  const int srow = l >> 2;
  const int scel = ((l & 3) ^ ((l >> 3) & 3)) << 3;
  const u16* ag = Xb + (size_t)(bm + 32 * w + srow) * 1024 + scel;
  const u16* bg = wz + (size_t)(bn + 32 * w + srow) * 1024 + scel;
  u16* ad = Alds + w * 1024;
  u16* bd = Blds + w * 1024;

  const int m0w = (w >> 1) * 64, n0w = (w & 1) * 64;
  const int swz = ((c >> 1) & 3) << 4;  // SWV(row) for row%16==c

  f32x4 acc[4][4] = {};

  for (int kk = 0; kk < 1024; kk += 32) {
    __syncthreads();
    GLD16(ag + kk, ad);
    GLD16(ag + kk + 16 * 1024, ad + 512);
    GLD16(bg + kk, bd);
    GLD16(bg + kk + 16 * 1024, bd + 512);
    asm volatile("s_waitcnt vmcnt(0)" ::: "memory");
    __syncthreads();

    short8 af[4], bf[4];
#pragma unroll
    for (int i = 0; i < 4; ++i) {
      const int off = (m0w + 16 * i + c) * 64 + ((g << 4) ^ swz);
      af[i] = *(const short8*)((const char*)Alds + off);
    }
#pragma unroll
    for (int j = 0; j < 4; ++j) {
      const int off = (n0w + 16 * j + c) * 64 + ((g << 4) ^ swz);
      bf[j] = *(const short8*)((const char*)Blds + off);
    }
#pragma unroll
    for (int i = 0; i < 4; ++i)
#pragma unroll
      for (int j = 0; j < 4; ++j)
        acc[i][j] = MFMA_BF16_16x16x32(af[i], bf[j], acc[i][j], 0, 0, 0);
  }

  u16* outz = qkv + (size_t)z * 8388608;
#pragma unroll
  for (int j = 0; j < 4; ++j) {
    const int n = bn + n0w + 16 * j + c;     // D col = lane&15
    const float bvv = bias[n];
    const int hoff = (n >> 6) * 131072;      // head * S * HD
    const int d = n & 63;
#pragma unroll
    for (int i = 0; i < 4; ++i) {
      const int mb = bm + m0w + 16 * i + 4 * g;  // D row = 4g + r
#pragma unroll
      for (int r = 0; r < 4; ++r) {
        const int m = mb + r;
        const float val = acc[i][j][r] + bvv;
        int idx = (m >> 11) * 2097152 + hoff;  // (b*16+h)*131072
        if (z < 2) idx += (m & 2047) * 64 + d;     // [.., s, d]
        else       idx += d * 2048 + (m & 2047);   // V^T: [.., d, s]
        outz[idx] = f2bf(val);
      }
    }
  }
}

// ---------------------------------------------------------------------------
// Kernel 2: flash attention.  Block = 4 waves; wave owns 32 q-rows (2 x 16).
// Swapped QK^T: D = mfma(A=K, B=Q) -> P^T with col=q=lane&15 (softmax stats
// lane-local).  K rows fed permuted (m -> 8*(m>>2)+(m&3) [+4]) so the two
// 16-row score frags concatenate into the K=32 PV fragment: p8[j] = key 8g+j.
// PV swapped too: ctx^T = mfma(A=V^T, B=P^T); corr/l stay lane-local.
// K tile [32][64] (128B rows, swizzle SW=((r&3)<<4)|((r&8)<<3));
// V^T tile [64][32] (64B rows, swizzle SWV=((r>>1)&3)<<4).  Both staged via
// global_load_lds with pre-swizzled per-lane source addresses.
__global__ __launch_bounds__(256) void attn_fwd(const u16* __restrict__ Qg,
                                                const u16* __restrict__ Kg,
                                                const u16* __restrict__ VTg,
                                                const float* __restrict__ mask,
                                                float* __restrict__ out) {
  __shared__ u16 Klds[2048];  // 32 keys x 64 hd
  __shared__ u16 Vlds[2048];  // 64 hd x 32 keys
  const int tid = threadIdx.x;
  const int l = tid & 63, w = tid >> 6;
  const int c = l & 15, g = l >> 4;
  const int hb = blockIdx.y, b = hb >> 4, h = hb & 15;
  const int q0 = blockIdx.x * 128 + w * 32;

  const u16* Qh = Qg + (size_t)hb * 131072;
  const u16* Kh = Kg + (size_t)hb * 131072;
  const u16* Vh = VTg + (size_t)hb * 131072;
  const float* mrow = mask + b * 2048;

  // Q fragments (B-operand: n=q=lane&15, k=hd=8g+j+32ks), kept in registers.
  short8 qf[2][2];
#pragma unroll
  for (int sub = 0; sub < 2; ++sub)
#pragma unroll
    for (int ks = 0; ks < 2; ++ks)
      qf[sub][ks] =
          *(const short8*)(Qh + (q0 + sub * 16 + c) * 64 + ks * 32 + g * 8);

  f32x4 ctx[2][4] = {};
  float m_run[2] = {-1e30f, -1e30f};
  float l_run[2] = {0.f, 0.f};

  // K staging: lane -> row 8w+(l>>3); pre-swizzled source col
  const int krow = 8 * w + (l >> 3);
  const int kcel =
      ((((l & 7) << 4) ^ (((l >> 3) & 3) << 4) ^ ((w & 1) << 6)) >> 1);
  const u16* kg = Kh + krow * 64 + kcel;
  u16* ksd = Klds + w * 512;
  // V^T staging: lane -> row 16w+(l>>2)
  const int vrow = 16 * w + (l >> 2);
  const int vcel = ((((l & 3) ^ ((l >> 3) & 3)) << 4) >> 1);
  const u16* vg = Vh + vrow * 2048 + vcel;
  u16* vsd = Vlds + w * 512;

  const int r0 = 8 * (c >> 2) + (c & 3);                 // permuted K row base
  const int swk = ((c & 3) << 4) | (((c >> 2) & 1) << 6);  // SW(row) read side
  const int swv = ((c >> 1) & 3) << 4;                     // SWV(16t+c)

  for (int it = 0; it < 64; ++it) {
    const int key0 = it << 5;
    __syncthreads();
    GLD16(kg + key0 * 64, ksd);
    GLD16(vg + key0, vsd);
    asm volatile("s_waitcnt vmcnt(0)" ::: "memory");
    __syncthreads();

    short8 af[2][2];  // K A-frags (f = permuted row set, ks = k split)
#pragma unroll
    for (int f = 0; f < 2; ++f) {
      const int row = r0 + 4 * f;
#pragma unroll
      for (int ks = 0; ks < 2; ++ks) {
        const int off = row * 128 + (((g << 4) + (ks << 6)) ^ swk);
        af[f][ks] = *(const short8*)((const char*)Klds + off);
      }
    }
    short8 vf[4];  // V^T A-frags (hd tile t)
#pragma unroll
    for (int t = 0; t < 4; ++t) {
      const int off = (16 * t + c) * 64 + ((g << 4) ^ swv);
      vf[t] = *(const short8*)((const char*)Vlds + off);
    }
    const f32x4 mv0 = *(const f32x4*)(mrow + key0 + 8 * g);
    const f32x4 mv1 = *(const f32x4*)(mrow + key0 + 8 * g + 4);

#pragma unroll
    for (int sub = 0; sub < 2; ++sub) {
      f32x4 s0 = {0.f, 0.f, 0.f, 0.f}, s1 = {0.f, 0.f, 0.f, 0.f};
      s0 = MFMA_BF16_16x16x32(af[0][0], qf[sub][0], s0, 0, 0, 0);
      s0 = MFMA_BF16_16x16x32(af[0][1], qf[sub][1], s0, 0, 0, 0);
      s1 = MFMA_BF16_16x16x32(af[1][0], qf[sub][0], s1, 0, 0, 0);
      s1 = MFMA_BF16_16x16x32(af[1][1], qf[sub][1], s1, 0, 0, 0);
      // lane holds keys 8g+{0..3} (s0) and 8g+{4..7} (s1) for q = c
      float sc[8];
#pragma unroll
      for (int r = 0; r < 4; ++r) {
        sc[r] = s0[r] * 0.125f + mv0[r];
        sc[r + 4] = s1[r] * 0.125f + mv1[r];
      }
      float mx = sc[0];
#pragma unroll
      for (int jj = 1; jj < 8; ++jj) mx = fmaxf(mx, sc[jj]);
      mx = fmaxf(mx, __shfl_xor(mx, 16));
      mx = fmaxf(mx, __shfl_xor(mx, 32));
      const float mnew = fmaxf(m_run[sub], mx);
      const float corr = __expf(m_run[sub] - mnew);
      m_run[sub] = mnew;
      float ls = 0.f;
      short8 p8;
#pragma unroll
      for (int jj = 0; jj < 8; ++jj) {
        const float p = __expf(sc[jj] - mnew);
        ls += p;
        p8[jj] = (short)f2bf(p);
      }
      ls += __shfl_xor(ls, 16);
      ls += __shfl_xor(ls, 32);
      l_run[sub] = l_run[sub] * corr + ls;
#pragma unroll
      for (int t = 0; t < 4; ++t) {
        ctx[sub][t] *= corr;
        ctx[sub][t] = MFMA_BF16_16x16x32(vf[t], p8, ctx[sub][t], 0, 0, 0);
      }
    }
  }

  // ctx^T: lane holds q = c, hd = 16t + 4g + r.  out fp32 [B,S,HID].
#pragma unroll
  for (int sub = 0; sub < 2; ++sub) {
    const float inv = 1.0f / l_run[sub];
    float* op = out + ((size_t)(b * 2048 + q0 + sub * 16 + c)) * 1024 +
                h * 64 + 4 * g;
#pragma unroll
    for (int t = 0; t < 4; ++t) {
      f32x4 o = ctx[sub][t] * inv;
      *(f32x4*)(op + t * 16) = o;
    }
  }
}

// ---------------------------------------------------------------------------
extern "C" void kernel_launch(void* const* d_in, const int* in_sizes, int n_in,
                              void* d_out, int out_size, void* d_ws,
                              size_t ws_size, hipStream_t stream) {
  (void)in_sizes; (void)n_in; (void)out_size; (void)ws_size;
  const float* hidden = (const float*)d_in[0];
  const float* mask = (const float*)d_in[1];
  const float* Wq = (const float*)d_in[2];
  const float* bq = (const float*)d_in[3];
  const float* Wk = (const float*)d_in[4];
  const float* bk = (const float*)d_in[5];
  const float* Wv = (const float*)d_in[6];
  const float* bv = (const float*)d_in[7];
  float* out = (float*)d_out;
  char* ws = (char*)d_ws;
  // ws layout (needs 70 MB): Xbf16 @0 (16MB) | Wt @16MB (6MB) | Q,K,V^T @22MB (48MB)
  u16* xbf = (u16*)(ws);
  u16* wt = (u16*)(ws + 16777216);
  u16* qkv = (u16*)(ws + 23068672);

  hipLaunchKernelGGL(conv_x_k, dim3(8192), dim3(256), 0, stream, hidden, xbf);
  hipLaunchKernelGGL(wtrans_k, dim3(1536), dim3(256), 0, stream, Wq, Wk, Wv, wt);
  hipLaunchKernelGGL(qkv_gemm, dim3(24, 64), dim3(256), 0, stream, xbf, wt, bq,
                     bk, bv, qkv);
  hipLaunchKernelGGL(attn_fwd, dim3(16, 64), dim3(256), 0, stream, qkv,
                     qkv + 8388608, qkv + 16777216, mask, out);
}

// Round 7
// 309.285 us; speedup vs baseline: 1.0969x; 1.0969x over previous
//
#include <hip/hip_runtime.h>
#include <stdint.h>

// BertSelfAttention fused forward, MI355X/gfx950.
// R4: attn VALU diet (cvt_pk_bf16, exp2-domain softmax, defer-max THR=8),
// 2-phase double-buffered K/V staging; qkv_gemm BK=64 (m97 config); packed
// V^T epilogue stores; mask pre-scaled by log2(e) in mask_k.

typedef float  f32x4  __attribute__((ext_vector_type(4)));
typedef short  short8 __attribute__((ext_vector_type(8)));
typedef unsigned short u16;
typedef u16    u16x4  __attribute__((ext_vector_type(4)));
typedef u16    u16x8  __attribute__((ext_vector_type(8)));
typedef unsigned int u32x4 __attribute__((ext_vector_type(4)));

#define MFMA_BF16_16x16x32 __builtin_amdgcn_mfma_f32_16x16x32_bf16

// global->LDS direct copy, 16B per lane; LDS dest must be wave-uniform base.
#define GLD16(gp, sp)                                                          \
  __builtin_amdgcn_global_load_lds(                                            \
      (const __attribute__((address_space(1))) void*)(gp),                     \
      (__attribute__((address_space(3))) void*)(sp), 16, 0, 0)

__device__ __forceinline__ u16 f2bf(float f) {  // RNE fp32->bf16
  unsigned u = __float_as_uint(f);
  return (u16)((u + 0x7FFFu + ((u >> 16) & 1u)) >> 16);
}

__device__ __forceinline__ unsigned cvt_pk_bf16(float lo, float hi) {
  unsigned r;
  asm("v_cvt_pk_bf16_f32 %0, %1, %2" : "=v"(r) : "v"(lo), "v"(hi));
  return r;
}

__device__ __forceinline__ float exp2fast(float x) {
#if __has_builtin(__builtin_amdgcn_exp2f)
  return __builtin_amdgcn_exp2f(x);
#else
  return exp2f(x);
#endif
}

// ---------------------------------------------------------------------------
// Kernel 0a: X [8192,1024] fp32 -> bf16.  8192 blocks * 256 thr * 4 elems.
__global__ __launch_bounds__(256) void conv_x_k(const float* __restrict__ x,
                                                u16* __restrict__ xb) {
  const int i = (blockIdx.x * 256 + threadIdx.x) * 4;
  const f32x4 v = *(const f32x4*)(x + i);
  u16x4 o;
#pragma unroll
  for (int j = 0; j < 4; ++j) o[j] = f2bf(v[j]);
  *(u16x4*)(xb + i) = o;
}

// ---------------------------------------------------------------------------
// Kernel 0b: Wt[z][n][k] = bf16(W_z[k][n]).  Coalesced reads (lanes span n).
__global__ __launch_bounds__(256) void wtrans_k(const float* __restrict__ Wq,
                                                const float* __restrict__ Wk,
                                                const float* __restrict__ Wv,
                                                u16* __restrict__ Wt) {
  const int bx = blockIdx.x;
  const int z = bx >> 9;
  const float* W = (z == 0) ? Wq : ((z == 1) ? Wk : Wv);
  const int r = ((bx & 511) << 8) | threadIdx.x;  // 0..131071
  const int kc = r >> 10;                         // 0..127 (8 k's each)
  const int n = r & 1023;
  u16x8 o;
#pragma unroll
  for (int j = 0; j < 8; ++j) o[j] = f2bf(W[(kc * 8 + j) * 1024 + n]);
  *(u16x8*)(Wt + (size_t)z * 1048576 + n * 1024 + kc * 8) = o;
}

// ---------------------------------------------------------------------------
// Kernel 0c: mask2 = mask * log2(e)  (8192 floats).
__global__ __launch_bounds__(256) void mask_k(const float* __restrict__ m,
                                              float* __restrict__ m2) {
  const int i = (blockIdx.x * 256 + threadIdx.x) * 4;
  f32x4 v = *(const f32x4*)(m + i);
  *(f32x4*)(m2 + i) = v * 1.4426950408889634f;
}

// ---------------------------------------------------------------------------
// Kernel 1: C_z = X * W_z + b_z.  128x128 tile, BK=64 (m97 config), 4 waves
// of 64x64.  LDS [128][64] per operand, XOR-swizzled in 16B quads:
// LDS[row][q] = global[row][q ^ (row&7)]; staged via global_load_lds with
// pre-swizzled per-lane SOURCE (linear dest).  Read side XORs the same key.
// z<2 -> [B,NH,S,HD] bf16; z==2 -> V^T [B,NH,HD,S] bf16 (u16x4-packed).
__global__ __launch_bounds__(256) void qkv_gemm(
    const u16* __restrict__ Xb, const u16* __restrict__ Wt,
    const float* __restrict__ bq, const float* __restrict__ bk,
    const float* __restrict__ bv, u16* __restrict__ qkv) {
  __shared__ u16 Alds[8192];  // [128][64] swizzled
  __shared__ u16 Blds[8192];  // [128][64] swizzled (rows = n)
  const int tid = threadIdx.x;
  const int l = tid & 63, w = tid >> 6;
  const int c = l & 15, g = l >> 4;
  const int nz = blockIdx.x;          // 0..23
  const int z = nz >> 3;
  const int bn = (nz & 7) << 7;
  const int bm = blockIdx.y << 7;
  const u16* wz = Wt + (size_t)z * 1048576;
  const float* bias = (z == 0) ? bq : ((z == 1) ? bk : bv);

  // staging: wave w rows 32w..32w+31, 128B rows, 8 GLD16 per iter.
  // lane l -> row (l>>3), LDS quad (l&7), source quad (l&7)^(l>>3).
  const int srow = l >> 3;                   // 0..7
  const int sq = ((l & 7) ^ srow) << 3;      // source elem offset
  const u16* ag = Xb + (size_t)(bm + 32 * w + srow) * 1024 + sq;
  const u16* bg = wz + (size_t)(bn + 32 * w + srow) * 1024 + sq;
  u16* ad = Alds + w * 2048;
  u16* bd = Blds + w * 2048;

  const int m0w = (w >> 1) * 64, n0w = (w & 1) * 64;
  const int swq = (c & 7) << 4;  // read-side byte XOR (row&7 == c&7)

  f32x4 acc[4][4] = {};

  for (int kk = 0; kk < 1024; kk += 64) {
    __syncthreads();
#pragma unroll
    for (int n = 0; n < 4; ++n) {
      GLD16(ag + kk + n * 8192, ad + n * 512);
      GLD16(bg + kk + n * 8192, bd + n * 512);
    }
    asm volatile("s_waitcnt vmcnt(0)" ::: "memory");
    __syncthreads();

    short8 af[4][2], bf[4][2];
#pragma unroll
    for (int i = 0; i < 4; ++i)
#pragma unroll
      for (int ks = 0; ks < 2; ++ks)
        af[i][ks] = *(const short8*)((const char*)Alds +
                                     (m0w + 16 * i + c) * 128 +
                                     (((ks << 6) | (g << 4)) ^ swq));
#pragma unroll
    for (int j = 0; j < 4; ++j)
#pragma unroll
      for (int ks = 0; ks < 2; ++ks)
        bf[j][ks] = *(const short8*)((const char*)Blds +
                                     (n0w + 16 * j + c) * 128 +
                                     (((ks << 6) | (g << 4)) ^ swq));
#pragma unroll
    for (int ks = 0; ks < 2; ++ks)
#pragma unroll
      for (int i = 0; i < 4; ++i)
#pragma unroll
        for (int j = 0; j < 4; ++j)
          acc[i][j] = MFMA_BF16_16x16x32(af[i][ks], bf[j][ks], acc[i][j], 0, 0, 0);
  }

  u16* outz = qkv + (size_t)z * 8388608;
  if (z == 2) {  // V^T: consecutive r = consecutive s -> u16x4 stores
#pragma unroll
    for (int j = 0; j < 4; ++j) {
      const int n = bn + n0w + 16 * j + c;
      const float bvv = bias[n];
      const int hoff = (n >> 6) * 131072;
      const int d = n & 63;
#pragma unroll
      for (int i = 0; i < 4; ++i) {
        const int mb = bm + m0w + 16 * i + 4 * g;
        u16x4 o4;
#pragma unroll
        for (int r = 0; r < 4; ++r) o4[r] = f2bf(acc[i][j][r] + bvv);
        *(u16x4*)(outz + (size_t)((mb >> 11) * 2097152 + hoff + d * 2048 +
                                  (mb & 2047))) = o4;
      }
    }
  } else {
#pragma unroll
    for (int j = 0; j < 4; ++j) {
      const int n = bn + n0w + 16 * j + c;
      const float bvv = bias[n];
      const int hoff = (n >> 6) * 131072;
      const int d = n & 63;
#pragma unroll
      for (int i = 0; i < 4; ++i) {
        const int mb = bm + m0w + 16 * i + 4 * g;
#pragma unroll
        for (int r = 0; r < 4; ++r) {
          const int m = mb + r;
          outz[(m >> 11) * 2097152 + hoff + (m & 2047) * 64 + d] =
              f2bf(acc[i][j][r] + bvv);
        }
      }
    }
  }
}

// ---------------------------------------------------------------------------
// Kernel 2: flash attention, exp2-domain softmax, defer-max, double-buffered
// K/V staging.  Block = 4 waves; wave owns 32 q-rows (2 x 16).
// Swapped QK^T: D = mfma(A=K, B=Q) -> P^T, q = lane&15 (stats lane-local).
// K rows permuted (m -> 8*(m>>2)+(m&3) [+4]) so the two 16-row score frags
// concatenate into the K=32 PV fragment: p8[j] = key 8g+j.
// PV swapped: ctx^T = mfma(A=V^T, B=P^T).
__global__ __launch_bounds__(256) void attn_fwd(const u16* __restrict__ Qg,
                                                const u16* __restrict__ Kg,
                                                const u16* __restrict__ VTg,
                                                const float* __restrict__ mask2,
                                                float* __restrict__ out) {
  __shared__ u16 Klds[2][2048];  // 32 keys x 64 hd, double-buffered
  __shared__ u16 Vlds[2][2048];  // 64 hd x 32 keys, double-buffered
  const int tid = threadIdx.x;
  const int l = tid & 63, w = tid >> 6;
  const int c = l & 15, g = l >> 4;
  const int hb = blockIdx.y, b = hb >> 4, h = hb & 15;
  const int q0 = blockIdx.x * 128 + w * 32;
  const float SCL = 0.1803368801111601f;  // log2(e)/8

  const u16* Qh = Qg + (size_t)hb * 131072;
  const u16* Kh = Kg + (size_t)hb * 131072;
  const u16* Vh = VTg + (size_t)hb * 131072;
  const float* mrow = mask2 + b * 2048;

  // Q fragments (B-operand: n=q=lane&15, k=hd=8g+j+32ks), in registers.
  short8 qf[2][2];
#pragma unroll
  for (int sub = 0; sub < 2; ++sub)
#pragma unroll
    for (int ks = 0; ks < 2; ++ks)
      qf[sub][ks] =
          *(const short8*)(Qh + (q0 + sub * 16 + c) * 64 + ks * 32 + g * 8);

  f32x4 ctx[2][4] = {};
  float m_run[2] = {-1e30f, -1e30f};
  float l_run[2] = {0.f, 0.f};

  // K staging: lane -> row 8w+(l>>3); pre-swizzled source col.
  const int krow = 8 * w + (l >> 3);
  const int kcel =
      ((((l & 7) << 4) ^ (((l >> 3) & 3) << 4) ^ ((w & 1) << 6)) >> 1);
  const u16* kg = Kh + krow * 64 + kcel;
  // V^T staging: lane -> row 16w+(l>>2).
  const int vrow = 16 * w + (l >> 2);
  const int vcel = ((((l & 3) ^ ((l >> 3) & 3)) << 4) >> 1);
  const u16* vg = Vh + vrow * 2048 + vcel;

  const int r0 = 8 * (c >> 2) + (c & 3);                   // permuted K row
  const int swk = ((c & 3) << 4) | (((c >> 2) & 1) << 6);  // K read XOR
  const int swv = ((c >> 1) & 3) << 4;                     // V read XOR

  // prologue: stage tile 0 into buffer 0.
  GLD16(kg, Klds[0] + (w << 9));
  GLD16(vg, Vlds[0] + (w << 9));
  asm volatile("s_waitcnt vmcnt(0)" ::: "memory");
  __syncthreads();

  for (int it = 0; it < 64; ++it) {
    const int cur = it & 1;
    const u16* Kb = Klds[cur];
    const u16* Vb = Vlds[cur];
    if (it < 63) {  // prefetch next tile into other buffer
      GLD16(kg + (it + 1) * 2048, Klds[cur ^ 1] + (w << 9));
      GLD16(vg + (it + 1) * 32, Vlds[cur ^ 1] + (w << 9));
    }

    short8 af[2][2];  // K A-frags (f = permuted row set, ks = k split)
#pragma unroll
    for (int f = 0; f < 2; ++f) {
      const int row = r0 + 4 * f;
#pragma unroll
      for (int ks = 0; ks < 2; ++ks) {
        const int off = row * 128 + (((g << 4) + (ks << 6)) ^ swk);
        af[f][ks] = *(const short8*)((const char*)Kb + off);
      }
    }
    short8 vf[4];  // V^T A-frags (hd tile t)
#pragma unroll
    for (int t = 0; t < 4; ++t) {
      const int off = (16 * t + c) * 64 + ((g << 4) ^ swv);
      vf[t] = *(const short8*)((const char*)Vb + off);
    }
    const f32x4 mv0 = *(const f32x4*)(mrow + (it << 5) + 8 * g);
    const f32x4 mv1 = *(const f32x4*)(mrow + (it << 5) + 8 * g + 4);

#pragma unroll
    for (int sub = 0; sub < 2; ++sub) {
      f32x4 s0 = {0.f, 0.f, 0.f, 0.f}, s1 = {0.f, 0.f, 0.f, 0.f};
      s0 = MFMA_BF16_16x16x32(af[0][0], qf[sub][0], s0, 0, 0, 0);
      s0 = MFMA_BF16_16x16x32(af[0][1], qf[sub][1], s0, 0, 0, 0);
      s1 = MFMA_BF16_16x16x32(af[1][0], qf[sub][0], s1, 0, 0, 0);
      s1 = MFMA_BF16_16x16x32(af[1][1], qf[sub][1], s1, 0, 0, 0);
      // lane holds keys 8g+{0..3} (s0) and 8g+{4..7} (s1) for q = c,
      // already in log2 domain after SCL/mask2.
      float sc[8];
#pragma unroll
      for (int r = 0; r < 4; ++r) {
        sc[r] = s0[r] * SCL + mv0[r];
        sc[r + 4] = s1[r] * SCL + mv1[r];
      }
      float mx = fmaxf(fmaxf(fmaxf(sc[0], sc[1]), fmaxf(sc[2], sc[3])),
                       fmaxf(fmaxf(sc[4], sc[5]), fmaxf(sc[6], sc[7])));
      mx = fmaxf(mx, __shfl_xor(mx, 16));
      mx = fmaxf(mx, __shfl_xor(mx, 32));
      // defer-max (T13): only rescale when the tile max grew by > 8.
      if (!__all(mx <= m_run[sub] + 8.f)) {
        const float mnew = fmaxf(m_run[sub], mx);
        const float corr = exp2fast(m_run[sub] - mnew);
        m_run[sub] = mnew;
        l_run[sub] *= corr;
#pragma unroll
        for (int t = 0; t < 4; ++t) ctx[sub][t] *= corr;
      }
      const float mcur = m_run[sub];
      float p[8];
      float ls = 0.f;
#pragma unroll
      for (int jj = 0; jj < 8; ++jj) {
        p[jj] = exp2fast(sc[jj] - mcur);
        ls += p[jj];
      }
      ls += __shfl_xor(ls, 16);
      ls += __shfl_xor(ls, 32);
      l_run[sub] += ls;
      u32x4 pu;
      pu[0] = cvt_pk_bf16(p[0], p[1]);
      pu[1] = cvt_pk_bf16(p[2], p[3]);
      pu[2] = cvt_pk_bf16(p[4], p[5]);
      pu[3] = cvt_pk_bf16(p[6], p[7]);
      const short8 p8 = __builtin_bit_cast(short8, pu);
#pragma unroll
      for (int t = 0; t < 4; ++t)
        ctx[sub][t] = MFMA_BF16_16x16x32(vf[t], p8, ctx[sub][t], 0, 0, 0);
    }

    asm volatile("s_waitcnt vmcnt(0)" ::: "memory");
    __syncthreads();
  }

  // ctx^T: lane holds q = c, hd = 16t + 4g + r.  out fp32 [B,S,HID].
#pragma unroll
  for (int sub = 0; sub < 2; ++sub) {
    const float inv = 1.0f / l_run[sub];
    float* op = out + ((size_t)(b * 2048 + q0 + sub * 16 + c)) * 1024 +
                h * 64 + 4 * g;
#pragma unroll
    for (int t = 0; t < 4; ++t) {
      f32x4 o = ctx[sub][t] * inv;
      *(f32x4*)(op + t * 16) = o;
    }
  }
}

// ---------------------------------------------------------------------------
extern "C" void kernel_launch(void* const* d_in, const int* in_sizes, int n_in,
                              void* d_out, int out_size, void* d_ws,
                              size_t ws_size, hipStream_t stream) {
  (void)in_sizes; (void)n_in; (void)out_size; (void)ws_size;
  const float* hidden = (const float*)d_in[0];
  const float* mask = (const float*)d_in[1];
  const float* Wq = (const float*)d_in[2];
  const float* bq = (const float*)d_in[3];
  const float* Wk = (const float*)d_in[4];
  const float* bk = (const float*)d_in[5];
  const float* Wv = (const float*)d_in[6];
  const float* bv = (const float*)d_in[7];
  float* out = (float*)d_out;
  char* ws = (char*)d_ws;
  // ws layout: Xbf16 @0 (16MB) | Wt @16MB (6MB) | Q,K,V^T @22MB (48MB).
  // mask2 reuses the Wt region (dead after qkv_gemm).
  u16* xbf = (u16*)(ws);
  u16* wt = (u16*)(ws + 16777216);
  float* mask2 = (float*)(ws + 16777216);
  u16* qkv = (u16*)(ws + 23068672);

  hipLaunchKernelGGL(conv_x_k, dim3(8192), dim3(256), 0, stream, hidden, xbf);
  hipLaunchKernelGGL(wtrans_k, dim3(1536), dim3(256), 0, stream, Wq, Wk, Wv, wt);
  hipLaunchKernelGGL(qkv_gemm, dim3(24, 64), dim3(256), 0, stream, xbf, wt, bq,
                     bk, bv, qkv);
  hipLaunchKernelGGL(mask_k, dim3(8), dim3(256), 0, stream, mask, mask2);
  hipLaunchKernelGGL(attn_fwd, dim3(16, 64), dim3(256), 0, stream, qkv,
                     qkv + 8388608, qkv + 16777216, mask2, out);
}